// Round 1
// baseline (578.449 us; speedup 1.0000x reference)
//
#include <hip/hip_runtime.h>

#define NODES_CH 128   // IN_CH == HID == 128
#define OUTW 64

// ---------------- CSR build ----------------

__global__ void k_zero(int* __restrict__ p, int n) {
    int i = blockIdx.x * blockDim.x + threadIdx.x;
    if (i < n) p[i] = 0;
}

__global__ void k_degree(const int* __restrict__ dstI, int* __restrict__ deg, int E) {
    int e = blockIdx.x * blockDim.x + threadIdx.x;
    if (e < E) atomicAdd(&deg[dstI[e]], 1);
}

// single-block exclusive scan (N up to ~any; 50000 here), also inits cursor
__global__ __launch_bounds__(1024)
void k_scan(const int* __restrict__ deg, int* __restrict__ rp,
            int* __restrict__ cursor, int n) {
    __shared__ int wsum[16];
    int tid  = threadIdx.x;
    int lane = tid & 63;
    int wid  = tid >> 6;
    int carry = 0;
    for (int base = 0; base < n; base += 1024) {
        int i = base + tid;
        int v = (i < n) ? deg[i] : 0;
        int x = v;
        #pragma unroll
        for (int off = 1; off < 64; off <<= 1) {
            int t = __shfl_up(x, off, 64);
            if (lane >= off) x += t;
        }
        if (lane == 63) wsum[wid] = x;
        __syncthreads();
        if (wid == 0) {
            int y = (lane < 16) ? wsum[lane] : 0;
            #pragma unroll
            for (int off = 1; off < 16; off <<= 1) {
                int t = __shfl_up(y, off, 64);
                if (lane >= off) y += t;
            }
            if (lane < 16) wsum[lane] = y;
        }
        __syncthreads();
        int woff  = (wid > 0) ? wsum[wid - 1] : 0;
        int incl  = x + woff;
        int total = wsum[15];
        if (i < n) {
            int ex = carry + incl - v;
            rp[i] = ex;
            cursor[i] = ex;
        }
        carry += total;
        __syncthreads();  // protect wsum before next chunk overwrites
    }
    if (tid == 0) rp[n] = carry;
}

__global__ void k_fill(const int* __restrict__ srcI, const int* __restrict__ dstI,
                       int* __restrict__ cursor, int* __restrict__ colA, int E) {
    int e = blockIdx.x * blockDim.x + threadIdx.x;
    if (e < E) {
        int d = dstI[e];
        int p = atomicAdd(&cursor[d], 1);
        colA[p] = srcI[e];
    }
}

// ---------------- mean aggregation (gather over CSR) ----------------
// one block (128 thr) per node; 2 edge-slots x 64 float2-channel-slots
__global__ __launch_bounds__(128)
void k_agg(const float* __restrict__ X, const int* __restrict__ rp,
           const int* __restrict__ colA, float* __restrict__ out, int n) {
    int node = blockIdx.x;
    int t  = threadIdx.x;
    int es = t >> 6;   // 0/1: which half of the edges
    int cs = t & 63;   // float2 slot within the 128-wide row
    int beg = rp[node], end = rp[node + 1];
    int deg = end - beg;
    const float2* X2 = (const float2*)X;
    float2 s = make_float2(0.f, 0.f);
    __shared__ int    idx[128];
    __shared__ float2 part[64];
    for (int base = beg; base < end; base += 128) {
        int m = min(128, end - base);
        __syncthreads();
        if (t < m) idx[t] = colA[base + t];
        __syncthreads();
        for (int e = es; e < m; e += 2) {
            float2 v = X2[(size_t)idx[e] * 64 + cs];
            s.x += v.x;
            s.y += v.y;
        }
    }
    if (es == 1) part[cs] = s;
    __syncthreads();
    if (es == 0) {
        float2 o = part[cs];
        float  c = (deg > 0) ? (float)deg : 1.f;
        float2 r;
        r.x = (s.x + o.x) / c;
        r.y = (s.y + o.y) / c;
        ((float2*)out)[(size_t)node * 64 + cs] = r;
    }
}

// ---------------- fused SAGE linear: out = A0@W(phase0) + A1@W(phase1) + b ----------------
// MODE 0: layer 1 -> out0 = relu(mean@W1_l + b1 + x@W1_r), 128 cols
// MODE 1: layer 2 -> virtual 128 cols = [mu(64) | logstd(64)], split outputs
// block: 256 thr = 16 colgroups(8 cols) x 16 rowgroups(8 rows) -> 128-row tile
template <int MODE>
__global__ __launch_bounds__(256, 2)
void k_gemm(const float* __restrict__ A0, const float* __restrict__ A1,
            const float* __restrict__ Wa0, const float* __restrict__ Wb0,
            const float* __restrict__ Wa1, const float* __restrict__ Wb1,
            const float* __restrict__ ba, const float* __restrict__ bb,
            float* __restrict__ out0, float* __restrict__ out1, int N) {
    __shared__ float Wlds[128 * 128];  // 64 KiB
    int tid = threadIdx.x;
    int cg  = tid & 15;
    int rg  = tid >> 4;
    int rbase = blockIdx.x * 128 + rg * 8;

    float acc[8][8];
    #pragma unroll
    for (int r = 0; r < 8; r++)
        #pragma unroll
        for (int c = 0; c < 8; c++) acc[r][c] = 0.f;

    for (int phase = 0; phase < 2; ++phase) {
        __syncthreads();  // previous phase's reads done before restage
        if (MODE == 0) {
            const float* W = phase ? Wa1 : Wa0;
            for (int i = tid; i < 128 * 32; i += 256)
                ((float4*)Wlds)[i] = ((const float4*)W)[i];
        } else {
            const float* WA = phase ? Wa1 : Wa0;  // mu weights [128][64]
            const float* WB = phase ? Wb1 : Wb0;  // logstd weights [128][64]
            for (int i = tid; i < 128 * 32; i += 256) {
                int k  = i >> 5;
                int c4 = i & 31;
                const float* s = (c4 < 16) ? (WA + k * 64 + c4 * 4)
                                           : (WB + k * 64 + (c4 - 16) * 4);
                ((float4*)Wlds)[i] = *(const float4*)s;
            }
        }
        __syncthreads();
        const float* A = phase ? A1 : A0;
        for (int k = 0; k < 128; k += 4) {
            float4 a[8];
            #pragma unroll
            for (int r = 0; r < 8; r++) {
                int row = rbase + r;
                a[r] = (row < N) ? *(const float4*)(A + (size_t)row * 128 + k)
                                 : make_float4(0.f, 0.f, 0.f, 0.f);
            }
            #pragma unroll
            for (int kk = 0; kk < 4; kk++) {
                float4 w0 = *(const float4*)(Wlds + (k + kk) * 128 + cg * 8);
                float4 w1 = *(const float4*)(Wlds + (k + kk) * 128 + cg * 8 + 4);
                #pragma unroll
                for (int r = 0; r < 8; r++) {
                    float av = (kk == 0) ? a[r].x : (kk == 1) ? a[r].y
                             : (kk == 2) ? a[r].z : a[r].w;
                    acc[r][0] += av * w0.x;
                    acc[r][1] += av * w0.y;
                    acc[r][2] += av * w0.z;
                    acc[r][3] += av * w0.w;
                    acc[r][4] += av * w1.x;
                    acc[r][5] += av * w1.y;
                    acc[r][6] += av * w1.z;
                    acc[r][7] += av * w1.w;
                }
            }
        }
    }

    // epilogue: bias (+relu for MODE 0), store
    const float* bptr = (MODE == 0) ? (ba + cg * 8)
                        : ((cg < 8) ? (ba + cg * 8) : (bb + (cg - 8) * 8));
    float4 bv0 = *(const float4*)bptr;
    float4 bv1 = *(const float4*)(bptr + 4);
    #pragma unroll
    for (int r = 0; r < 8; r++) {
        int row = rbase + r;
        if (row >= N) continue;
        float v[8];
        v[0] = acc[r][0] + bv0.x; v[1] = acc[r][1] + bv0.y;
        v[2] = acc[r][2] + bv0.z; v[3] = acc[r][3] + bv0.w;
        v[4] = acc[r][4] + bv1.x; v[5] = acc[r][5] + bv1.y;
        v[6] = acc[r][6] + bv1.z; v[7] = acc[r][7] + bv1.w;
        if (MODE == 0) {
            #pragma unroll
            for (int c = 0; c < 8; c++) v[c] = fmaxf(v[c], 0.f);
            float4* o = (float4*)(out0 + (size_t)row * 128 + cg * 8);
            o[0] = make_float4(v[0], v[1], v[2], v[3]);
            o[1] = make_float4(v[4], v[5], v[6], v[7]);
        } else {
            float* obase = (cg < 8) ? (out0 + (size_t)row * 64 + cg * 8)
                                    : (out1 + (size_t)row * 64 + (cg - 8) * 8);
            float4* o = (float4*)obase;
            o[0] = make_float4(v[0], v[1], v[2], v[3]);
            o[1] = make_float4(v[4], v[5], v[6], v[7]);
        }
    }
}

// ---------------- launch ----------------

extern "C" void kernel_launch(void* const* d_in, const int* in_sizes, int n_in,
                              void* d_out, int out_size, void* d_ws, size_t ws_size,
                              hipStream_t stream) {
    const float* x     = (const float*)d_in[0];
    const int*   ei    = (const int*)d_in[1];
    const float* W1_l  = (const float*)d_in[2];
    const float* b1    = (const float*)d_in[3];
    const float* W1_r  = (const float*)d_in[4];
    const float* Wmu_l = (const float*)d_in[5];
    const float* bmu   = (const float*)d_in[6];
    const float* Wmu_r = (const float*)d_in[7];
    const float* Wls_l = (const float*)d_in[8];
    const float* bls   = (const float*)d_in[9];
    const float* Wls_r = (const float*)d_in[10];

    const int N = in_sizes[0] / NODES_CH;  // 50000
    const int E = in_sizes[1] / 2;         // 800000
    const int* srcI = ei;
    const int* dstI = ei + E;

    const int NP = (N + 63) & ~63;   // padded for alignment
    const int EP = (E + 15) & ~15;

    char* w = (char*)d_ws;
    int* deg    = (int*)w;  w += (size_t)NP * 4;
    int* rp     = (int*)w;  w += (size_t)(NP + 64) * 4;
    int* cursor = (int*)w;  w += (size_t)NP * 4;
    int* colA   = (int*)w;  w += (size_t)EP * 4;
    float* meanb = (float*)w;  w += (size_t)N * 128 * 4;
    float* h     = (float*)w;  w += (size_t)N * 128 * 4;

    float* out_mu = (float*)d_out;
    float* out_ls = out_mu + (size_t)N * OUTW;

    // CSR build
    k_zero<<<(N + 255) / 256, 256, 0, stream>>>(deg, N);
    k_degree<<<(E + 255) / 256, 256, 0, stream>>>(dstI, deg, E);
    k_scan<<<1, 1024, 0, stream>>>(deg, rp, cursor, N);
    k_fill<<<(E + 255) / 256, 256, 0, stream>>>(srcI, dstI, cursor, colA, E);

    const int gblocks = (N + 127) / 128;

    // layer 1: h = relu(mean(x) @ W1_l + b1 + x @ W1_r)
    k_agg<<<N, 128, 0, stream>>>(x, rp, colA, meanb, N);
    k_gemm<0><<<gblocks, 256, 0, stream>>>(meanb, x, W1_l, nullptr, W1_r, nullptr,
                                           b1, b1, h, nullptr, N);

    // layer 2: mu / logstd share mean(h)
    k_agg<<<N, 128, 0, stream>>>(h, rp, colA, meanb, N);
    k_gemm<1><<<gblocks, 256, 0, stream>>>(meanb, h, Wmu_l, Wls_l, Wmu_r, Wls_r,
                                           bmu, bls, out_mu, out_ls, N);
}